// Round 18
// baseline (633.054 us; speedup 1.0000x reference)
//
#include <hip/hip_runtime.h>
#include <hip/hip_fp16.h>

// SGCNet fp16 pipeline, round 17 (= R16 + atomic-free stats GEMM at grid 1024):
//  - stats GEMM: per-block partial rows (no global atomics) -> bn_final reduces
//    1024x256 partials. Grid 320 -> 1024 (1.25 -> 4 waves/SIMD).
//  - gsum memsets dropped (partials fully overwritten each launch).
//  - spmm / CSR build / conversions unchanged from R16.

typedef _Float16 f16x8 __attribute__((ext_vector_type(8)));
typedef __attribute__((ext_vector_type(4))) float f32x4;

#define HR_RBITS 16
#define HR_RSIZE 65536           // nodes per range
#define HR_NRANGE 2              // 2*65536 >= 100000
#define HR_NCHUNK 128
#define HR_WPC (HR_NRANGE * HR_RSIZE / 4)  // byte-counter words per chunk = 32768

#define PA_NCHUNK 256
#define PB_SHIFT 8               // 256 nodes per bucket
#define GEMM_STATS_GRID 1024

static inline size_t align256(size_t x) { return (x + 255) & ~(size_t)255; }

__device__ inline unsigned int packh2(float a, float b) {
    return (unsigned int)__half_as_ushort(__float2half(a)) |
           ((unsigned int)__half_as_ushort(__float2half(b)) << 16);
}

// acc += (f16 lo/hi of u) * w   [f32 accumulate, mixed-precision FMA]
__device__ inline void fmamix_lo(float& acc, unsigned int u, float w) {
    asm("v_fma_mix_f32 %0, %1, %2, %0 op_sel_hi:[1,0,0]"
        : "+v"(acc) : "v"(u), "v"(w));
}
__device__ inline void fmamix_hi(float& acc, unsigned int u, float w) {
    asm("v_fma_mix_f32 %0, %1, %2, %0 op_sel:[1,0,0] op_sel_hi:[1,0,0]"
        : "+v"(acc) : "v"(u), "v"(w));
}

// ---------------- degree histogram (row), 8-bit packed LDS counters ----------------
__global__ void hist_row_kernel(const int* __restrict__ row, int E,
                                unsigned int* __restrict__ staging) {
    __shared__ unsigned int l32[HR_RSIZE / 4];  // 64 KB: 4 nodes per word
    int range = blockIdx.x % HR_NRANGE;
    int chunk = blockIdx.x / HR_NRANGE;
    for (int i = threadIdx.x; i < HR_RSIZE / 4; i += 256) l32[i] = 0;
    __syncthreads();
    int lo = range << HR_RBITS;
    int q4 = E >> 2;
    int ebeg = (int)(((long long)q4 * chunk / HR_NCHUNK) << 2);
    int eend = (int)(((long long)q4 * (chunk + 1) / HR_NCHUNK) << 2);
    for (int i = ebeg + threadIdx.x * 4; i + 3 < eend; i += 256 * 4) {
        int4 v = *(const int4*)(row + i);
        unsigned a;
        a = (unsigned)(v.x - lo); if (a < HR_RSIZE) atomicAdd(&l32[a >> 2], 1u << ((a & 3) * 8));
        a = (unsigned)(v.y - lo); if (a < HR_RSIZE) atomicAdd(&l32[a >> 2], 1u << ((a & 3) * 8));
        a = (unsigned)(v.z - lo); if (a < HR_RSIZE) atomicAdd(&l32[a >> 2], 1u << ((a & 3) * 8));
        a = (unsigned)(v.w - lo); if (a < HR_RSIZE) atomicAdd(&l32[a >> 2], 1u << ((a & 3) * 8));
    }
    if (chunk == HR_NCHUNK - 1) {
        for (int i = (E & ~3) + threadIdx.x; i < E; i += 256) {
            unsigned a = (unsigned)(row[i] - lo);
            if (a < HR_RSIZE) atomicAdd(&l32[a >> 2], 1u << ((a & 3) * 8));
        }
    }
    __syncthreads();
    unsigned int* dst = staging + (size_t)chunk * HR_WPC + (lo >> 2);
    for (int i = threadIdx.x; i < HR_RSIZE / 4; i += 256) dst[i] = l32[i];
}

__global__ void dis_kernel(const unsigned int* __restrict__ staging, float* __restrict__ dis, int n) {
    int i = blockIdx.x * blockDim.x + threadIdx.x;
    if (i < n) {
        int shift = (i & 3) * 8;
        int d = 0;
#pragma unroll 4
        for (int c = 0; c < HR_NCHUNK; ++c)
            d += (staging[(size_t)c * HR_WPC + (i >> 2)] >> shift) & 0xff;
        dis[i] = d > 0 ? rsqrtf((float)d) : 0.f;
    }
}

// ---------------- pass A: partition edges by dest bucket (node>>8) ----------------

__global__ void pa_hist_kernel(const int* __restrict__ col, int E,
                               int* __restrict__ chunkhist, int nbuck) {
    __shared__ int lh[512];
    int chunk = blockIdx.x;
    for (int i = threadIdx.x; i < nbuck; i += 256) lh[i] = 0;
    __syncthreads();
    int ebeg = (int)((long long)E * chunk / PA_NCHUNK);
    int eend = (int)((long long)E * (chunk + 1) / PA_NCHUNK);
    for (int i = ebeg + threadIdx.x; i < eend; i += 256)
        atomicAdd(&lh[col[i] >> PB_SHIFT], 1);
    __syncthreads();
    for (int i = threadIdx.x; i < nbuck; i += 256)
        chunkhist[i * PA_NCHUNK + chunk] = lh[i];   // bucket-major
}

__global__ void pa_scan1_kernel(int* __restrict__ chunkhist, int* __restrict__ tot) {
    __shared__ int sh[PA_NCHUNK];
    int b = blockIdx.x, t = threadIdx.x;
    int* p = chunkhist + b * PA_NCHUNK;
    int v = p[t];
    sh[t] = v;
    __syncthreads();
    for (int off = 1; off < PA_NCHUNK; off <<= 1) {
        int tv = (t >= off) ? sh[t - off] : 0;
        __syncthreads();
        sh[t] += tv;
        __syncthreads();
    }
    p[t] = sh[t] - v;
    if (t == PA_NCHUNK - 1) tot[b] = sh[t];
}

__global__ void pa_scan2_kernel(const int* __restrict__ tot, int* __restrict__ bucketstart,
                                int nbuck) {
    __shared__ int sh[512];
    int t = threadIdx.x;
    int v = (t < nbuck) ? tot[t] : 0;
    sh[t] = v;
    __syncthreads();
    for (int off = 1; off < 512; off <<= 1) {
        int tv = (t >= off) ? sh[t - off] : 0;
        __syncthreads();
        sh[t] += tv;
        __syncthreads();
    }
    if (t < nbuck) bucketstart[t] = sh[t] - v;
    if (t == 511) bucketstart[nbuck] = sh[511];
}

// part entry packed: (r << 8) | (c & 255)
__global__ void pa_scatter_kernel(const int* __restrict__ row, const int* __restrict__ col,
                                  int E, const int* __restrict__ chunkhist,
                                  const int* __restrict__ bucketstart,
                                  int* __restrict__ part, int nbuck) {
    __shared__ int loff[512];
    int chunk = blockIdx.x;
    for (int i = threadIdx.x; i < nbuck; i += 256)
        loff[i] = chunkhist[i * PA_NCHUNK + chunk] + bucketstart[i];
    __syncthreads();
    int ebeg = (int)((long long)E * chunk / PA_NCHUNK);
    int eend = (int)((long long)E * (chunk + 1) / PA_NCHUNK);
    for (int i = ebeg + threadIdx.x; i < eend; i += 256) {
        int r = row[i], c = col[i];
        int pos = atomicAdd(&loff[c >> PB_SHIFT], 1);
        part[pos] = (r << 8) | (c & 255);
    }
}

// ---------------- pass B: rank within bucket -> exact CSR (f32 weights) ----------------
__global__ void pb_kernel(const int* __restrict__ part, const int* __restrict__ bucketstart,
                          const float* __restrict__ dis, int2* __restrict__ csr,
                          int* __restrict__ csr_ptr, int n) {
    __shared__ int lcnt[256], sh[256], loff[256];
    int b = blockIdx.x, t = threadIdx.x;
    int nlo = b << PB_SHIFT;
    int ebeg = bucketstart[b], eend = bucketstart[b + 1];
    lcnt[t] = 0;
    __syncthreads();
    for (int i = ebeg + t; i < eend; i += 256)
        atomicAdd(&lcnt[part[i] & 255], 1);
    __syncthreads();
    int v = lcnt[t];
    sh[t] = v;
    __syncthreads();
    for (int off = 1; off < 256; off <<= 1) {
        int tv = (t >= off) ? sh[t - off] : 0;
        __syncthreads();
        sh[t] += tv;
        __syncthreads();
    }
    int excl = sh[t] - v;
    loff[t] = excl;
    if (nlo + t <= n) csr_ptr[nlo + t] = ebeg + excl;
    __syncthreads();
    for (int i = ebeg + t; i < eend; i += 256) {
        int e = part[i];
        int cl8 = e & 255;
        int r = (int)((unsigned)e >> 8);
        int slot = atomicAdd(&loff[cl8], 1);
        int2 o;
        o.x = r;
        o.y = __float_as_int(dis[r] * dis[nlo + cl8]);   // full f32 weight
        csr[ebeg + slot] = o;
    }
}

// ---------------- conversions ----------------

__global__ void xcvt_kernel(const float* __restrict__ x, unsigned int* __restrict__ x16, int total4) {
    for (int i = blockIdx.x * blockDim.x + threadIdx.x; i < total4; i += gridDim.x * blockDim.x) {
        float4 f = ((const float4*)x)[i];
        x16[i * 2] = packh2(f.x, f.y);
        x16[i * 2 + 1] = packh2(f.z, f.w);
    }
}

__global__ void wcvt_kernel(const float* __restrict__ W1, const float* __restrict__ W2,
                            unsigned short* __restrict__ W1t, unsigned short* __restrict__ W2t) {
    int i = blockIdx.x * blockDim.x + threadIdx.x;
    if (i < 32768) {
        const float* W = (i < 16384) ? W1 : W2;
        unsigned short* T = (i < 16384) ? W1t : W2t;
        int j = i & 16383;
        int k = j >> 7, c = j & 127;
        T[c * 128 + k] = __half_as_ushort(__float2half(W[j]));
    }
}

// ---------------- SpMM: per-lane entries + dwordx4 gathers + fma_mix ----------------

template <bool AFF>
__global__ void spmm16_kernel(const int* __restrict__ csr_ptr, const int2* __restrict__ csr,
                              const unsigned short* __restrict__ h_in,
                              const float* __restrict__ scale, const float* __restrict__ shift,
                              unsigned short* __restrict__ h_out, int n) {
    int gw = __builtin_amdgcn_readfirstlane((blockIdx.x * blockDim.x + threadIdx.x) >> 6);
    int lane = threadIdx.x & 63;
    int sub = lane & 15;
    int grp = lane >> 4;
    if (gw >= n) return;
    uint4* outp = (uint4*)(h_out + (size_t)gw * 128) + sub;
    int beg = csr_ptr[gw];
    int end = csr_ptr[gw + 1];
    int cnt = end - beg;
    if (cnt == 0) {
        if (lane < 16) {
            uint4 z = {0u, 0u, 0u, 0u};
            *outp = z;
        }
        return;
    }
    const int2* base = csr + beg;
    const unsigned short* hb = h_in + sub * 8;   // per-lane column base
    float acc[8];
#pragma unroll
    for (int j = 0; j < 8; ++j) acc[j] = 0.f;
    float wsum = 0.f;
    for (int j0 = 0; j0 < cnt; j0 += 16) {
        int2 ent[4];
#pragma unroll
        for (int k = 0; k < 4; ++k) ent[k] = base[j0 + 4 * k + grp];  // csr padded; 16-way bcast
        uint4 u[4];
        float w[4];
#pragma unroll
        for (int k = 0; k < 4; ++k) {
            bool v = (j0 + 4 * k + grp) < cnt;
            int idx = v ? ent[k].x : 0;
            w[k] = v ? __int_as_float(ent[k].y) : 0.f;
            u[k] = *(const uint4*)(hb + (size_t)((unsigned)idx * 128u));
        }
#pragma unroll
        for (int k = 0; k < 4; ++k) {
            if (AFF) wsum += w[k];
            fmamix_lo(acc[0], u[k].x, w[k]);
            fmamix_hi(acc[1], u[k].x, w[k]);
            fmamix_lo(acc[2], u[k].y, w[k]);
            fmamix_hi(acc[3], u[k].y, w[k]);
            fmamix_lo(acc[4], u[k].z, w[k]);
            fmamix_hi(acc[5], u[k].z, w[k]);
            fmamix_lo(acc[6], u[k].w, w[k]);
            fmamix_hi(acc[7], u[k].w, w[k]);
        }
    }
#pragma unroll
    for (int j = 0; j < 8; ++j) {
        acc[j] += __shfl_xor(acc[j], 16, 64);
        acc[j] += __shfl_xor(acc[j], 32, 64);
    }
    if (AFF) {
        wsum += __shfl_xor(wsum, 16, 64);
        wsum += __shfl_xor(wsum, 32, 64);
        float4 s0 = ((const float4*)scale)[sub * 2];
        float4 s1 = ((const float4*)scale)[sub * 2 + 1];
        float4 h0 = ((const float4*)shift)[sub * 2];
        float4 h1 = ((const float4*)shift)[sub * 2 + 1];
        acc[0] = fmaf(h0.x, wsum, s0.x * acc[0]);
        acc[1] = fmaf(h0.y, wsum, s0.y * acc[1]);
        acc[2] = fmaf(h0.z, wsum, s0.z * acc[2]);
        acc[3] = fmaf(h0.w, wsum, s0.w * acc[3]);
        acc[4] = fmaf(h1.x, wsum, s1.x * acc[4]);
        acc[5] = fmaf(h1.y, wsum, s1.y * acc[5]);
        acc[6] = fmaf(h1.z, wsum, s1.z * acc[6]);
        acc[7] = fmaf(h1.w, wsum, s1.w * acc[7]);
    }
    if (lane < 16) {
        uint4 o;
        o.x = packh2(acc[0], acc[1]);
        o.y = packh2(acc[2], acc[3]);
        o.z = packh2(acc[4], acc[5]);
        o.w = packh2(acc[6], acc[7]);
        *outp = o;
    }
}

// ---------------- MFMA GEMM  Y[n, NCT*16] = X[n,128]fp16 @ Wt + bias ----------------
// STATS: per-block partial sums written non-atomically to partials[blk][256]
// ([0:128)=col sums, [128:256)=col sumsq); bn_final reduces over blocks.

template <int NCT, bool OUTF32, bool STATS>
__launch_bounds__(256)
__global__ void gemm16_kernel(const unsigned short* __restrict__ X,
                              const unsigned short* __restrict__ Wt,
                              const float* __restrict__ bias, void* __restrict__ Y,
                              float* __restrict__ partials, int n) {
    __shared__ __align__(16) char lds[NCT * 16 * 256];
    __shared__ float ssum[NCT * 16], ssq[NCT * 16];
    for (int i = threadIdx.x; i < NCT * 16 * 16; i += 256) {
        int col = i >> 4;
        int kbyte = (i & 15) << 4;
        *(uint4*)(lds + col * 256 + (kbyte ^ ((col & 7) << 4))) = ((const uint4*)Wt)[i];
    }
    if (STATS) {
        for (int i = threadIdx.x; i < NCT * 16; i += 256) {
            ssum[i] = 0.f;
            ssq[i] = 0.f;
        }
    }
    __syncthreads();

    int lane = threadIdx.x & 63;
    int wave = threadIdx.x >> 6;
    int cl = lane & 15, g = lane >> 4;

    f16x8 b[NCT][4];
#pragma unroll
    for (int ct = 0; ct < NCT; ++ct) {
        int col = ct * 16 + cl;
#pragma unroll
        for (int kc = 0; kc < 4; ++kc) {
            int kbyte = kc * 64 + g * 16;
            b[ct][kc] = *(const f16x8*)(lds + col * 256 + (kbyte ^ ((col & 7) << 4)));
        }
    }
    float bc[NCT];
#pragma unroll
    for (int ct = 0; ct < NCT; ++ct) bc[ct] = bias[ct * 16 + cl];

    for (int rb0 = blockIdx.x * 64; rb0 < n; rb0 += gridDim.x * 64) {
        int rb = rb0 + wave * 16;
        if (rb >= n) continue;
        int row = rb + cl;
        int rowc = row < n ? row : n - 1;
        const unsigned short* xr = X + (size_t)rowc * 128;
        f16x8 a[4];
#pragma unroll
        for (int kc = 0; kc < 4; ++kc) a[kc] = *(const f16x8*)(xr + kc * 32 + g * 8);
#pragma unroll
        for (int ct = 0; ct < NCT; ++ct) {
            f32x4 acc = {bc[ct], bc[ct], bc[ct], bc[ct]};
#pragma unroll
            for (int kc = 0; kc < 4; ++kc)
                acc = __builtin_amdgcn_mfma_f32_16x16x32_f16(a[kc], b[ct][kc], acc, 0, 0, 0);
            int colo = ct * 16 + cl;
            if (STATS) {
                float s = acc[0] + acc[1] + acc[2] + acc[3];
                float q = acc[0] * acc[0] + acc[1] * acc[1] + acc[2] * acc[2] + acc[3] * acc[3];
                s += __shfl_xor(s, 16, 64);
                s += __shfl_xor(s, 32, 64);
                q += __shfl_xor(q, 16, 64);
                q += __shfl_xor(q, 32, 64);
                if (g == 0) {
                    atomicAdd(&ssum[colo], s);
                    atomicAdd(&ssq[colo], q);
                }
            }
#pragma unroll
            for (int i = 0; i < 4; ++i) {
                int ro = rb + g * 4 + i;
                if (ro < n) {
                    if (OUTF32)
                        ((float*)Y)[(size_t)ro * (NCT * 16) + colo] = acc[i];
                    else
                        ((unsigned short*)Y)[(size_t)ro * 128 + colo] =
                            __half_as_ushort(__float2half(acc[i]));
                }
            }
        }
    }
    if (STATS) {
        __syncthreads();
        float* pout = partials + (size_t)blockIdx.x * 256;
        int t = threadIdx.x;
        if (t < 256) pout[t] = (t < 128) ? ssum[t] : ssq[t - 128];
    }
}

// ---------------- BN finalize (reduces partials) / W3 fold ----------------

__global__ void bn_final_kernel(const float* __restrict__ partials, int nblk,
                                const float* __restrict__ gamma, const float* __restrict__ beta,
                                int n, float* __restrict__ scale, float* __restrict__ shift) {
    __shared__ float s[512];
    int t = threadIdx.x;           // 512 threads: (col, which, half)
    int col = t & 127;
    int which = (t >> 7) & 1;      // 0=sum, 1=sq
    int half = t >> 8;             // blocks split in two halves
    int b0 = half * (nblk / 2);
    int b1 = (half == 0) ? (nblk / 2) : nblk;
    float acc = 0.f;
    for (int b = b0; b < b1; ++b)
        acc += partials[(size_t)b * 256 + which * 128 + col];
    s[t] = acc;
    __syncthreads();
    if (t < 128) {
        float fn = (float)n;
        float sum = s[t] + s[t + 256];
        float sq = s[t + 128] + s[t + 384];
        float mu = sum / fn;
        float var = sq / fn - mu * mu;
        float inv = rsqrtf(var + 1e-5f);
        float sc = gamma[t] * inv;
        scale[t] = sc;
        shift[t] = beta[t] - sc * mu;
    }
}

__global__ void fold_w3_kernel(const float* __restrict__ W3, const float* __restrict__ b3,
                               const float* __restrict__ scale, const float* __restrict__ shift,
                               unsigned short* __restrict__ W3t, float* __restrict__ b3f) {
    int c = threadIdx.x;
    if (c < 64) {
        float acc = b3[c];
        for (int k = 0; k < 128; ++k) {
            float w = W3[k * 64 + c];
            W3t[c * 128 + k] = __half_as_ushort(__float2half(scale[k] * w));
            acc += shift[k] * w;
        }
        b3f[c] = acc;
    }
}

// ---------------- launch ----------------

extern "C" void kernel_launch(void* const* d_in, const int* in_sizes, int n_in,
                              void* d_out, int out_size, void* d_ws, size_t ws_size,
                              hipStream_t stream) {
    const float* x = (const float*)d_in[0];
    const int* edge = (const int*)d_in[1];
    const float* W1 = (const float*)d_in[2];
    const float* b1 = (const float*)d_in[3];
    const float* g1 = (const float*)d_in[4];
    const float* be1 = (const float*)d_in[5];
    const float* W2 = (const float*)d_in[6];
    const float* b2 = (const float*)d_in[7];
    const float* g2 = (const float*)d_in[8];
    const float* be2 = (const float*)d_in[9];
    const float* W3 = (const float*)d_in[10];
    const float* b3 = (const float*)d_in[11];
    float* out = (float*)d_out;

    const int N = in_sizes[0] / 128;
    const int E = in_sizes[1] / 2;
    const int* erow = edge;
    const int* ecol = edge + E;
    const int nbuck = (N + 255) >> PB_SHIFT;

    char* p = (char*)d_ws;
    size_t off = 0;
    auto carve = [&](size_t bytes) {
        void* r = p + off;
        off += align256(bytes);
        return r;
    };
    unsigned short* x16 = (unsigned short*)carve((size_t)N * 128 * 2);
    unsigned short* A16 = (unsigned short*)carve((size_t)N * 128 * 2);
    unsigned short* B16 = (unsigned short*)carve((size_t)N * 128 * 2);
    int* part = (int*)carve((size_t)E * 4);               // 6.4 MB ┐ staging (16.8 MB)
    int2* csr = (int2*)carve((size_t)E * 8 + 256);        // 12.8 MB┘ aliases these two
    int* csr_ptr = (int*)carve((size_t)(N + 1) * 4);
    int* chunkhist = (int*)carve((size_t)(nbuck + 1) * PA_NCHUNK * 4);
    int* bucketstart = (int*)carve((size_t)(nbuck + 1) * 4);
    int* tot = (int*)carve((size_t)(nbuck + 1) * 4);
    float* dis = (float*)carve((size_t)N * 4);
    float* partials = (float*)carve((size_t)GEMM_STATS_GRID * 256 * 4);  // 1 MB
    float* scale1 = (float*)carve(512);
    float* shift1 = (float*)carve(512);
    float* scale2 = (float*)carve(512);
    float* shift2 = (float*)carve(512);
    unsigned short* W1t = (unsigned short*)carve(128 * 128 * 2);
    unsigned short* W2t = (unsigned short*)carve(128 * 128 * 2);
    unsigned short* W3t = (unsigned short*)carve(64 * 128 * 2);
    float* b3f = (float*)carve(256);
    // staging for hist_row: 16.8 MB, aliases part+csr (19.2 MB); staging dead
    // after dis_kernel; part/csr written later (stream-ordered).
    unsigned int* staging = (unsigned int*)part;
    (void)ws_size;

    const int TB = 256;
    const int gN = (N + TB - 1) / TB;
    const int gSp = (N + 3) / 4;
    const int gGemm = (N + 63) / 64;

    // --- graph structure: degrees + two-level counting sort -> exact CSR ---
    hist_row_kernel<<<HR_NRANGE * HR_NCHUNK, TB, 0, stream>>>(erow, E, staging);
    dis_kernel<<<gN, TB, 0, stream>>>(staging, dis, N);
    pa_hist_kernel<<<PA_NCHUNK, TB, 0, stream>>>(ecol, E, chunkhist, nbuck);
    pa_scan1_kernel<<<nbuck, PA_NCHUNK, 0, stream>>>(chunkhist, tot);
    pa_scan2_kernel<<<1, 512, 0, stream>>>(tot, bucketstart, nbuck);
    pa_scatter_kernel<<<PA_NCHUNK, TB, 0, stream>>>(erow, ecol, E, chunkhist, bucketstart, part, nbuck);
    pb_kernel<<<nbuck, TB, 0, stream>>>(part, bucketstart, dis, csr, csr_ptr, N);

    // --- conversions ---
    xcvt_kernel<<<2048, TB, 0, stream>>>(x, (unsigned int*)x16, N * 32);
    wcvt_kernel<<<128, TB, 0, stream>>>(W1, W2, W1t, W2t);

    // --- h = A^2 x ---
    spmm16_kernel<false><<<gSp, TB, 0, stream>>>(csr_ptr, csr, x16, nullptr, nullptr, A16, N);
    spmm16_kernel<false><<<gSp, TB, 0, stream>>>(csr_ptr, csr, A16, nullptr, nullptr, B16, N);

    // --- Y1 = h W1 + b1 (fp16) with fused BN1 stats (atomic-free partials) ---
    gemm16_kernel<8, false, true><<<GEMM_STATS_GRID, TB, 0, stream>>>(B16, W1t, b1, A16, partials, N);
    bn_final_kernel<<<1, 512, 0, stream>>>(partials, GEMM_STATS_GRID, g1, be1, N, scale1, shift1);

    // --- h = A^2 BN1(Y1) ---
    spmm16_kernel<true><<<gSp, TB, 0, stream>>>(csr_ptr, csr, A16, scale1, shift1, B16, N);
    spmm16_kernel<false><<<gSp, TB, 0, stream>>>(csr_ptr, csr, B16, nullptr, nullptr, A16, N);

    // --- Y2 = h W2 + b2 (fp16) with fused BN2 stats ---
    gemm16_kernel<8, false, true><<<GEMM_STATS_GRID, TB, 0, stream>>>(A16, W2t, b2, B16, partials, N);
    bn_final_kernel<<<1, 512, 0, stream>>>(partials, GEMM_STATS_GRID, g2, be2, N, scale2, shift2);

    // --- out = BN2(Y2) W3 + b3 ---
    fold_w3_kernel<<<1, 64, 0, stream>>>(W3, b3, scale2, shift2, W3t, b3f);
    gemm16_kernel<4, true, false><<<gGemm, TB, 0, stream>>>(B16, W3t, b3f, out, nullptr, N);
}

// Round 19
// 386.163 us; speedup vs baseline: 1.6393x; 1.6393x over previous
//
#include <hip/hip_runtime.h>
#include <hip/hip_fp16.h>

// SGCNet fp16 pipeline, round 18 (= R17 with PARALLEL partials reduction):
//  - R17's single-block bn_final was a 512-deep serial load chain (137us x2).
//    Replaced by bn_final with one block PER COLUMN (128 blocks x 256 thr).
//  - stats GEMM (atomic-free partials, grid 1024) retained.
//  - spmm / CSR build / conversions unchanged.

typedef _Float16 f16x8 __attribute__((ext_vector_type(8)));
typedef __attribute__((ext_vector_type(4))) float f32x4;

#define HR_RBITS 16
#define HR_RSIZE 65536           // nodes per range
#define HR_NRANGE 2              // 2*65536 >= 100000
#define HR_NCHUNK 128
#define HR_WPC (HR_NRANGE * HR_RSIZE / 4)  // byte-counter words per chunk = 32768

#define PA_NCHUNK 256
#define PB_SHIFT 8               // 256 nodes per bucket
#define GEMM_STATS_GRID 1024

static inline size_t align256(size_t x) { return (x + 255) & ~(size_t)255; }

__device__ inline unsigned int packh2(float a, float b) {
    return (unsigned int)__half_as_ushort(__float2half(a)) |
           ((unsigned int)__half_as_ushort(__float2half(b)) << 16);
}

// acc += (f16 lo/hi of u) * w   [f32 accumulate, mixed-precision FMA]
__device__ inline void fmamix_lo(float& acc, unsigned int u, float w) {
    asm("v_fma_mix_f32 %0, %1, %2, %0 op_sel_hi:[1,0,0]"
        : "+v"(acc) : "v"(u), "v"(w));
}
__device__ inline void fmamix_hi(float& acc, unsigned int u, float w) {
    asm("v_fma_mix_f32 %0, %1, %2, %0 op_sel:[1,0,0] op_sel_hi:[1,0,0]"
        : "+v"(acc) : "v"(u), "v"(w));
}

// ---------------- degree histogram (row), 8-bit packed LDS counters ----------------
__global__ void hist_row_kernel(const int* __restrict__ row, int E,
                                unsigned int* __restrict__ staging) {
    __shared__ unsigned int l32[HR_RSIZE / 4];  // 64 KB: 4 nodes per word
    int range = blockIdx.x % HR_NRANGE;
    int chunk = blockIdx.x / HR_NRANGE;
    for (int i = threadIdx.x; i < HR_RSIZE / 4; i += 256) l32[i] = 0;
    __syncthreads();
    int lo = range << HR_RBITS;
    int q4 = E >> 2;
    int ebeg = (int)(((long long)q4 * chunk / HR_NCHUNK) << 2);
    int eend = (int)(((long long)q4 * (chunk + 1) / HR_NCHUNK) << 2);
    for (int i = ebeg + threadIdx.x * 4; i + 3 < eend; i += 256 * 4) {
        int4 v = *(const int4*)(row + i);
        unsigned a;
        a = (unsigned)(v.x - lo); if (a < HR_RSIZE) atomicAdd(&l32[a >> 2], 1u << ((a & 3) * 8));
        a = (unsigned)(v.y - lo); if (a < HR_RSIZE) atomicAdd(&l32[a >> 2], 1u << ((a & 3) * 8));
        a = (unsigned)(v.z - lo); if (a < HR_RSIZE) atomicAdd(&l32[a >> 2], 1u << ((a & 3) * 8));
        a = (unsigned)(v.w - lo); if (a < HR_RSIZE) atomicAdd(&l32[a >> 2], 1u << ((a & 3) * 8));
    }
    if (chunk == HR_NCHUNK - 1) {
        for (int i = (E & ~3) + threadIdx.x; i < E; i += 256) {
            unsigned a = (unsigned)(row[i] - lo);
            if (a < HR_RSIZE) atomicAdd(&l32[a >> 2], 1u << ((a & 3) * 8));
        }
    }
    __syncthreads();
    unsigned int* dst = staging + (size_t)chunk * HR_WPC + (lo >> 2);
    for (int i = threadIdx.x; i < HR_RSIZE / 4; i += 256) dst[i] = l32[i];
}

__global__ void dis_kernel(const unsigned int* __restrict__ staging, float* __restrict__ dis, int n) {
    int i = blockIdx.x * blockDim.x + threadIdx.x;
    if (i < n) {
        int shift = (i & 3) * 8;
        int d = 0;
#pragma unroll 4
        for (int c = 0; c < HR_NCHUNK; ++c)
            d += (staging[(size_t)c * HR_WPC + (i >> 2)] >> shift) & 0xff;
        dis[i] = d > 0 ? rsqrtf((float)d) : 0.f;
    }
}

// ---------------- pass A: partition edges by dest bucket (node>>8) ----------------

__global__ void pa_hist_kernel(const int* __restrict__ col, int E,
                               int* __restrict__ chunkhist, int nbuck) {
    __shared__ int lh[512];
    int chunk = blockIdx.x;
    for (int i = threadIdx.x; i < nbuck; i += 256) lh[i] = 0;
    __syncthreads();
    int ebeg = (int)((long long)E * chunk / PA_NCHUNK);
    int eend = (int)((long long)E * (chunk + 1) / PA_NCHUNK);
    for (int i = ebeg + threadIdx.x; i < eend; i += 256)
        atomicAdd(&lh[col[i] >> PB_SHIFT], 1);
    __syncthreads();
    for (int i = threadIdx.x; i < nbuck; i += 256)
        chunkhist[i * PA_NCHUNK + chunk] = lh[i];   // bucket-major
}

__global__ void pa_scan1_kernel(int* __restrict__ chunkhist, int* __restrict__ tot) {
    __shared__ int sh[PA_NCHUNK];
    int b = blockIdx.x, t = threadIdx.x;
    int* p = chunkhist + b * PA_NCHUNK;
    int v = p[t];
    sh[t] = v;
    __syncthreads();
    for (int off = 1; off < PA_NCHUNK; off <<= 1) {
        int tv = (t >= off) ? sh[t - off] : 0;
        __syncthreads();
        sh[t] += tv;
        __syncthreads();
    }
    p[t] = sh[t] - v;
    if (t == PA_NCHUNK - 1) tot[b] = sh[t];
}

__global__ void pa_scan2_kernel(const int* __restrict__ tot, int* __restrict__ bucketstart,
                                int nbuck) {
    __shared__ int sh[512];
    int t = threadIdx.x;
    int v = (t < nbuck) ? tot[t] : 0;
    sh[t] = v;
    __syncthreads();
    for (int off = 1; off < 512; off <<= 1) {
        int tv = (t >= off) ? sh[t - off] : 0;
        __syncthreads();
        sh[t] += tv;
        __syncthreads();
    }
    if (t < nbuck) bucketstart[t] = sh[t] - v;
    if (t == 511) bucketstart[nbuck] = sh[511];
}

// part entry packed: (r << 8) | (c & 255)
__global__ void pa_scatter_kernel(const int* __restrict__ row, const int* __restrict__ col,
                                  int E, const int* __restrict__ chunkhist,
                                  const int* __restrict__ bucketstart,
                                  int* __restrict__ part, int nbuck) {
    __shared__ int loff[512];
    int chunk = blockIdx.x;
    for (int i = threadIdx.x; i < nbuck; i += 256)
        loff[i] = chunkhist[i * PA_NCHUNK + chunk] + bucketstart[i];
    __syncthreads();
    int ebeg = (int)((long long)E * chunk / PA_NCHUNK);
    int eend = (int)((long long)E * (chunk + 1) / PA_NCHUNK);
    for (int i = ebeg + threadIdx.x; i < eend; i += 256) {
        int r = row[i], c = col[i];
        int pos = atomicAdd(&loff[c >> PB_SHIFT], 1);
        part[pos] = (r << 8) | (c & 255);
    }
}

// ---------------- pass B: rank within bucket -> exact CSR (f32 weights) ----------------
__global__ void pb_kernel(const int* __restrict__ part, const int* __restrict__ bucketstart,
                          const float* __restrict__ dis, int2* __restrict__ csr,
                          int* __restrict__ csr_ptr, int n) {
    __shared__ int lcnt[256], sh[256], loff[256];
    int b = blockIdx.x, t = threadIdx.x;
    int nlo = b << PB_SHIFT;
    int ebeg = bucketstart[b], eend = bucketstart[b + 1];
    lcnt[t] = 0;
    __syncthreads();
    for (int i = ebeg + t; i < eend; i += 256)
        atomicAdd(&lcnt[part[i] & 255], 1);
    __syncthreads();
    int v = lcnt[t];
    sh[t] = v;
    __syncthreads();
    for (int off = 1; off < 256; off <<= 1) {
        int tv = (t >= off) ? sh[t - off] : 0;
        __syncthreads();
        sh[t] += tv;
        __syncthreads();
    }
    int excl = sh[t] - v;
    loff[t] = excl;
    if (nlo + t <= n) csr_ptr[nlo + t] = ebeg + excl;
    __syncthreads();
    for (int i = ebeg + t; i < eend; i += 256) {
        int e = part[i];
        int cl8 = e & 255;
        int r = (int)((unsigned)e >> 8);
        int slot = atomicAdd(&loff[cl8], 1);
        int2 o;
        o.x = r;
        o.y = __float_as_int(dis[r] * dis[nlo + cl8]);   // full f32 weight
        csr[ebeg + slot] = o;
    }
}

// ---------------- conversions ----------------

__global__ void xcvt_kernel(const float* __restrict__ x, unsigned int* __restrict__ x16, int total4) {
    for (int i = blockIdx.x * blockDim.x + threadIdx.x; i < total4; i += gridDim.x * blockDim.x) {
        float4 f = ((const float4*)x)[i];
        x16[i * 2] = packh2(f.x, f.y);
        x16[i * 2 + 1] = packh2(f.z, f.w);
    }
}

__global__ void wcvt_kernel(const float* __restrict__ W1, const float* __restrict__ W2,
                            unsigned short* __restrict__ W1t, unsigned short* __restrict__ W2t) {
    int i = blockIdx.x * blockDim.x + threadIdx.x;
    if (i < 32768) {
        const float* W = (i < 16384) ? W1 : W2;
        unsigned short* T = (i < 16384) ? W1t : W2t;
        int j = i & 16383;
        int k = j >> 7, c = j & 127;
        T[c * 128 + k] = __half_as_ushort(__float2half(W[j]));
    }
}

// ---------------- SpMM: per-lane entries + dwordx4 gathers + fma_mix ----------------

template <bool AFF>
__global__ void spmm16_kernel(const int* __restrict__ csr_ptr, const int2* __restrict__ csr,
                              const unsigned short* __restrict__ h_in,
                              const float* __restrict__ scale, const float* __restrict__ shift,
                              unsigned short* __restrict__ h_out, int n) {
    int gw = __builtin_amdgcn_readfirstlane((blockIdx.x * blockDim.x + threadIdx.x) >> 6);
    int lane = threadIdx.x & 63;
    int sub = lane & 15;
    int grp = lane >> 4;
    if (gw >= n) return;
    uint4* outp = (uint4*)(h_out + (size_t)gw * 128) + sub;
    int beg = csr_ptr[gw];
    int end = csr_ptr[gw + 1];
    int cnt = end - beg;
    if (cnt == 0) {
        if (lane < 16) {
            uint4 z = {0u, 0u, 0u, 0u};
            *outp = z;
        }
        return;
    }
    const int2* base = csr + beg;
    const unsigned short* hb = h_in + sub * 8;   // per-lane column base
    float acc[8];
#pragma unroll
    for (int j = 0; j < 8; ++j) acc[j] = 0.f;
    float wsum = 0.f;
    for (int j0 = 0; j0 < cnt; j0 += 16) {
        int2 ent[4];
#pragma unroll
        for (int k = 0; k < 4; ++k) ent[k] = base[j0 + 4 * k + grp];  // csr padded; 16-way bcast
        uint4 u[4];
        float w[4];
#pragma unroll
        for (int k = 0; k < 4; ++k) {
            bool v = (j0 + 4 * k + grp) < cnt;
            int idx = v ? ent[k].x : 0;
            w[k] = v ? __int_as_float(ent[k].y) : 0.f;
            u[k] = *(const uint4*)(hb + (size_t)((unsigned)idx * 128u));
        }
#pragma unroll
        for (int k = 0; k < 4; ++k) {
            if (AFF) wsum += w[k];
            fmamix_lo(acc[0], u[k].x, w[k]);
            fmamix_hi(acc[1], u[k].x, w[k]);
            fmamix_lo(acc[2], u[k].y, w[k]);
            fmamix_hi(acc[3], u[k].y, w[k]);
            fmamix_lo(acc[4], u[k].z, w[k]);
            fmamix_hi(acc[5], u[k].z, w[k]);
            fmamix_lo(acc[6], u[k].w, w[k]);
            fmamix_hi(acc[7], u[k].w, w[k]);
        }
    }
#pragma unroll
    for (int j = 0; j < 8; ++j) {
        acc[j] += __shfl_xor(acc[j], 16, 64);
        acc[j] += __shfl_xor(acc[j], 32, 64);
    }
    if (AFF) {
        wsum += __shfl_xor(wsum, 16, 64);
        wsum += __shfl_xor(wsum, 32, 64);
        float4 s0 = ((const float4*)scale)[sub * 2];
        float4 s1 = ((const float4*)scale)[sub * 2 + 1];
        float4 h0 = ((const float4*)shift)[sub * 2];
        float4 h1 = ((const float4*)shift)[sub * 2 + 1];
        acc[0] = fmaf(h0.x, wsum, s0.x * acc[0]);
        acc[1] = fmaf(h0.y, wsum, s0.y * acc[1]);
        acc[2] = fmaf(h0.z, wsum, s0.z * acc[2]);
        acc[3] = fmaf(h0.w, wsum, s0.w * acc[3]);
        acc[4] = fmaf(h1.x, wsum, s1.x * acc[4]);
        acc[5] = fmaf(h1.y, wsum, s1.y * acc[5]);
        acc[6] = fmaf(h1.z, wsum, s1.z * acc[6]);
        acc[7] = fmaf(h1.w, wsum, s1.w * acc[7]);
    }
    if (lane < 16) {
        uint4 o;
        o.x = packh2(acc[0], acc[1]);
        o.y = packh2(acc[2], acc[3]);
        o.z = packh2(acc[4], acc[5]);
        o.w = packh2(acc[6], acc[7]);
        *outp = o;
    }
}

// ---------------- MFMA GEMM  Y[n, NCT*16] = X[n,128]fp16 @ Wt + bias ----------------
// STATS: per-block partial sums written non-atomically to partials[blk][256].

template <int NCT, bool OUTF32, bool STATS>
__launch_bounds__(256)
__global__ void gemm16_kernel(const unsigned short* __restrict__ X,
                              const unsigned short* __restrict__ Wt,
                              const float* __restrict__ bias, void* __restrict__ Y,
                              float* __restrict__ partials, int n) {
    __shared__ __align__(16) char lds[NCT * 16 * 256];
    __shared__ float ssum[NCT * 16], ssq[NCT * 16];
    for (int i = threadIdx.x; i < NCT * 16 * 16; i += 256) {
        int col = i >> 4;
        int kbyte = (i & 15) << 4;
        *(uint4*)(lds + col * 256 + (kbyte ^ ((col & 7) << 4))) = ((const uint4*)Wt)[i];
    }
    if (STATS) {
        for (int i = threadIdx.x; i < NCT * 16; i += 256) {
            ssum[i] = 0.f;
            ssq[i] = 0.f;
        }
    }
    __syncthreads();

    int lane = threadIdx.x & 63;
    int wave = threadIdx.x >> 6;
    int cl = lane & 15, g = lane >> 4;

    f16x8 b[NCT][4];
#pragma unroll
    for (int ct = 0; ct < NCT; ++ct) {
        int col = ct * 16 + cl;
#pragma unroll
        for (int kc = 0; kc < 4; ++kc) {
            int kbyte = kc * 64 + g * 16;
            b[ct][kc] = *(const f16x8*)(lds + col * 256 + (kbyte ^ ((col & 7) << 4)));
        }
    }
    float bc[NCT];
#pragma unroll
    for (int ct = 0; ct < NCT; ++ct) bc[ct] = bias[ct * 16 + cl];

    for (int rb0 = blockIdx.x * 64; rb0 < n; rb0 += gridDim.x * 64) {
        int rb = rb0 + wave * 16;
        if (rb >= n) continue;
        int row = rb + cl;
        int rowc = row < n ? row : n - 1;
        const unsigned short* xr = X + (size_t)rowc * 128;
        f16x8 a[4];
#pragma unroll
        for (int kc = 0; kc < 4; ++kc) a[kc] = *(const f16x8*)(xr + kc * 32 + g * 8);
#pragma unroll
        for (int ct = 0; ct < NCT; ++ct) {
            f32x4 acc = {bc[ct], bc[ct], bc[ct], bc[ct]};
#pragma unroll
            for (int kc = 0; kc < 4; ++kc)
                acc = __builtin_amdgcn_mfma_f32_16x16x32_f16(a[kc], b[ct][kc], acc, 0, 0, 0);
            int colo = ct * 16 + cl;
            if (STATS) {
                float s = acc[0] + acc[1] + acc[2] + acc[3];
                float q = acc[0] * acc[0] + acc[1] * acc[1] + acc[2] * acc[2] + acc[3] * acc[3];
                s += __shfl_xor(s, 16, 64);
                s += __shfl_xor(s, 32, 64);
                q += __shfl_xor(q, 16, 64);
                q += __shfl_xor(q, 32, 64);
                if (g == 0) {
                    atomicAdd(&ssum[colo], s);
                    atomicAdd(&ssq[colo], q);
                }
            }
#pragma unroll
            for (int i = 0; i < 4; ++i) {
                int ro = rb + g * 4 + i;
                if (ro < n) {
                    if (OUTF32)
                        ((float*)Y)[(size_t)ro * (NCT * 16) + colo] = acc[i];
                    else
                        ((unsigned short*)Y)[(size_t)ro * 128 + colo] =
                            __half_as_ushort(__float2half(acc[i]));
                }
            }
        }
    }
    if (STATS) {
        __syncthreads();
        float* pout = partials + (size_t)blockIdx.x * 256;
        int t = threadIdx.x;
        if (t < 256) pout[t] = (t < 128) ? ssum[t] : ssq[t - 128];
    }
}

// ---------------- BN finalize: one block PER COLUMN over partials ----------------
// Block c (0..127), 256 threads: thread t accumulates blocks {t, t+256, t+512, t+768}
// for both sum (offset c) and sq (offset 128+c); LDS tree; thread 0 writes.

__global__ void bn_final_kernel(const float* __restrict__ partials, int nblk,
                                const float* __restrict__ gamma, const float* __restrict__ beta,
                                int n, float* __restrict__ scale, float* __restrict__ shift) {
    __shared__ float ssum[256], ssq[256];
    int c = blockIdx.x;
    int t = threadIdx.x;
    float s = 0.f, q = 0.f;
    for (int b = t; b < nblk; b += 256) {
        s += partials[(size_t)b * 256 + c];
        q += partials[(size_t)b * 256 + 128 + c];
    }
    ssum[t] = s;
    ssq[t] = q;
    __syncthreads();
    for (int off = 128; off > 0; off >>= 1) {
        if (t < off) {
            ssum[t] += ssum[t + off];
            ssq[t] += ssq[t + off];
        }
        __syncthreads();
    }
    if (t == 0) {
        float fn = (float)n;
        float mu = ssum[0] / fn;
        float var = ssq[0] / fn - mu * mu;
        float inv = rsqrtf(var + 1e-5f);
        float sc = gamma[c] * inv;
        scale[c] = sc;
        shift[c] = beta[c] - sc * mu;
    }
}

__global__ void fold_w3_kernel(const float* __restrict__ W3, const float* __restrict__ b3,
                               const float* __restrict__ scale, const float* __restrict__ shift,
                               unsigned short* __restrict__ W3t, float* __restrict__ b3f) {
    int c = threadIdx.x;
    if (c < 64) {
        float acc = b3[c];
        for (int k = 0; k < 128; ++k) {
            float w = W3[k * 64 + c];
            W3t[c * 128 + k] = __half_as_ushort(__float2half(scale[k] * w));
            acc += shift[k] * w;
        }
        b3f[c] = acc;
    }
}

// ---------------- launch ----------------

extern "C" void kernel_launch(void* const* d_in, const int* in_sizes, int n_in,
                              void* d_out, int out_size, void* d_ws, size_t ws_size,
                              hipStream_t stream) {
    const float* x = (const float*)d_in[0];
    const int* edge = (const int*)d_in[1];
    const float* W1 = (const float*)d_in[2];
    const float* b1 = (const float*)d_in[3];
    const float* g1 = (const float*)d_in[4];
    const float* be1 = (const float*)d_in[5];
    const float* W2 = (const float*)d_in[6];
    const float* b2 = (const float*)d_in[7];
    const float* g2 = (const float*)d_in[8];
    const float* be2 = (const float*)d_in[9];
    const float* W3 = (const float*)d_in[10];
    const float* b3 = (const float*)d_in[11];
    float* out = (float*)d_out;

    const int N = in_sizes[0] / 128;
    const int E = in_sizes[1] / 2;
    const int* erow = edge;
    const int* ecol = edge + E;
    const int nbuck = (N + 255) >> PB_SHIFT;

    char* p = (char*)d_ws;
    size_t off = 0;
    auto carve = [&](size_t bytes) {
        void* r = p + off;
        off += align256(bytes);
        return r;
    };
    unsigned short* x16 = (unsigned short*)carve((size_t)N * 128 * 2);
    unsigned short* A16 = (unsigned short*)carve((size_t)N * 128 * 2);
    unsigned short* B16 = (unsigned short*)carve((size_t)N * 128 * 2);
    int* part = (int*)carve((size_t)E * 4);               // 6.4 MB ┐ staging (16.8 MB)
    int2* csr = (int2*)carve((size_t)E * 8 + 256);        // 12.8 MB┘ aliases these two
    int* csr_ptr = (int*)carve((size_t)(N + 1) * 4);
    int* chunkhist = (int*)carve((size_t)(nbuck + 1) * PA_NCHUNK * 4);
    int* bucketstart = (int*)carve((size_t)(nbuck + 1) * 4);
    int* tot = (int*)carve((size_t)(nbuck + 1) * 4);
    float* dis = (float*)carve((size_t)N * 4);
    float* partials = (float*)carve((size_t)GEMM_STATS_GRID * 256 * 4);  // 1 MB
    float* scale1 = (float*)carve(512);
    float* shift1 = (float*)carve(512);
    float* scale2 = (float*)carve(512);
    float* shift2 = (float*)carve(512);
    unsigned short* W1t = (unsigned short*)carve(128 * 128 * 2);
    unsigned short* W2t = (unsigned short*)carve(128 * 128 * 2);
    unsigned short* W3t = (unsigned short*)carve(64 * 128 * 2);
    float* b3f = (float*)carve(256);
    // staging for hist_row: 16.8 MB, aliases part+csr (19.2 MB); staging dead
    // after dis_kernel; part/csr written later (stream-ordered).
    unsigned int* staging = (unsigned int*)part;
    (void)ws_size;

    const int TB = 256;
    const int gN = (N + TB - 1) / TB;
    const int gSp = (N + 3) / 4;
    const int gGemm = (N + 63) / 64;

    // --- graph structure: degrees + two-level counting sort -> exact CSR ---
    hist_row_kernel<<<HR_NRANGE * HR_NCHUNK, TB, 0, stream>>>(erow, E, staging);
    dis_kernel<<<gN, TB, 0, stream>>>(staging, dis, N);
    pa_hist_kernel<<<PA_NCHUNK, TB, 0, stream>>>(ecol, E, chunkhist, nbuck);
    pa_scan1_kernel<<<nbuck, PA_NCHUNK, 0, stream>>>(chunkhist, tot);
    pa_scan2_kernel<<<1, 512, 0, stream>>>(tot, bucketstart, nbuck);
    pa_scatter_kernel<<<PA_NCHUNK, TB, 0, stream>>>(erow, ecol, E, chunkhist, bucketstart, part, nbuck);
    pb_kernel<<<nbuck, TB, 0, stream>>>(part, bucketstart, dis, csr, csr_ptr, N);

    // --- conversions ---
    xcvt_kernel<<<2048, TB, 0, stream>>>(x, (unsigned int*)x16, N * 32);
    wcvt_kernel<<<128, TB, 0, stream>>>(W1, W2, W1t, W2t);

    // --- h = A^2 x ---
    spmm16_kernel<false><<<gSp, TB, 0, stream>>>(csr_ptr, csr, x16, nullptr, nullptr, A16, N);
    spmm16_kernel<false><<<gSp, TB, 0, stream>>>(csr_ptr, csr, A16, nullptr, nullptr, B16, N);

    // --- Y1 = h W1 + b1 (fp16) with fused BN1 stats (atomic-free partials) ---
    gemm16_kernel<8, false, true><<<GEMM_STATS_GRID, TB, 0, stream>>>(B16, W1t, b1, A16, partials, N);
    bn_final_kernel<<<128, TB, 0, stream>>>(partials, GEMM_STATS_GRID, g1, be1, N, scale1, shift1);

    // --- h = A^2 BN1(Y1) ---
    spmm16_kernel<true><<<gSp, TB, 0, stream>>>(csr_ptr, csr, A16, scale1, shift1, B16, N);
    spmm16_kernel<false><<<gSp, TB, 0, stream>>>(csr_ptr, csr, B16, nullptr, nullptr, A16, N);

    // --- Y2 = h W2 + b2 (fp16) with fused BN2 stats ---
    gemm16_kernel<8, false, true><<<GEMM_STATS_GRID, TB, 0, stream>>>(A16, W2t, b2, B16, partials, N);
    bn_final_kernel<<<128, TB, 0, stream>>>(partials, GEMM_STATS_GRID, g2, be2, N, scale2, shift2);

    // --- out = BN2(Y2) W3 + b3 ---
    fold_w3_kernel<<<1, 64, 0, stream>>>(W3, b3, scale2, shift2, W3t, b3f);
    gemm16_kernel<4, true, false><<<gGemm, TB, 0, stream>>>(B16, W3t, b3f, out, nullptr, N);
}